// Round 1
// 1428.267 us; speedup vs baseline: 1.1008x; 1.1008x over previous
//
#include <hip/hip_runtime.h>
#include <stdint.h>
#include <stddef.h>

// Problem dims (fixed by reference setup_inputs)
#define M_TOK 8192
#define K_IN  4096
#define N_OUT 11008
// ALPHA/R = 32/16 = 2.0

#define KT   (K_IN / 32)   // 128 K-tiles of BK=32
#define NTN  43            // N_OUT / 256
#define NTM  32            // M_TOK / 256
#define NWG  (NTN * NTM)   // 1376 blocks; 1376 % 8 == 0 -> simple XCD swizzle is bijective

typedef __attribute__((ext_vector_type(8))) short   short8;   // 8 bf16 (4 VGPRs) — MFMA A/B frag
typedef __attribute__((ext_vector_type(4))) float   floatx4;  // MFMA C/D frag

#define AS1(p) ((const __attribute__((address_space(1))) void*)(p))
#define AS3(p) ((__attribute__((address_space(3))) void*)(p))

__device__ __forceinline__ unsigned short f2bf_rne(float f) {
  union { float f; unsigned u; } v; v.f = f;
  unsigned r = v.u + 0x7FFFu + ((v.u >> 16) & 1u);  // round-to-nearest-even
  return (unsigned short)(r >> 16);
}

__device__ __forceinline__ unsigned long long pack4(float a, float b, float c, float d) {
  return (unsigned long long)f2bf_rne(a)
       | ((unsigned long long)f2bf_rne(b) << 16)
       | ((unsigned long long)f2bf_rne(c) << 32)
       | ((unsigned long long)f2bf_rne(d) << 48);
}

// ---- Kernel 1: cast x (fp32) -> bf16 scratch. float4 in, 8B out per thread.
__global__ void cast_x_kernel(const float* __restrict__ x,
                              unsigned long long* __restrict__ xb) {
  size_t idx = (size_t)blockIdx.x * blockDim.x + threadIdx.x;
  const float4 v = ((const float4*)x)[idx];
  xb[idx] = pack4(v.x, v.y, v.z, v.w);
}

// ---- Kernel 2: W' = bf16(W + 2 * B @ A).  One block = (row o, 1024-col chunk).
__global__ void wprime_kernel(const float* __restrict__ W,
                              const float* __restrict__ B,
                              const float* __restrict__ A,
                              unsigned long long* __restrict__ wp) {
  const int o   = blockIdx.x;
  const int col = blockIdx.y * 1024 + threadIdx.x * 4;
  float4 acc = *(const float4*)(W + (size_t)o * K_IN + col);
#pragma unroll
  for (int r = 0; r < 16; ++r) {
    const float b2 = 2.0f * B[o * 16 + r];   // block-uniform -> scalar load
    const float4 a4 = *(const float4*)(A + (size_t)r * K_IN + col);
    acc.x += b2 * a4.x; acc.y += b2 * a4.y;
    acc.z += b2 * a4.z; acc.w += b2 * a4.w;
  }
  wp[((size_t)o * K_IN + col) >> 2] = pack4(acc.x, acc.y, acc.z, acc.w);
}

// ---- Kernel 3: out[M,N] = Xb[M,K] @ Wp[N,K]^T + bias
// 256x256 tile, BK=32, 8 waves (2M x 4N), wave tile 128x64 (8x4 of 16x16x32 MFMA).
// 3-stage LDS pipeline (96 KiB), counted vmcnt(4), raw s_barrier (no drain),
// fragment-linear LDS (zero bank conflicts) via pre-permuted global source.
__global__ __launch_bounds__(512, 2) void lora_gemm(
    const unsigned short* __restrict__ Xb,
    const unsigned short* __restrict__ Wp,
    const float* __restrict__ bias,
    float* __restrict__ out) {
  // 3 buffers x (A: 1024 slots x16B | B: 1024 slots x16B) = 3 x 32 KiB.
  // Slot s of A holds X[m0 + (s>>6)*16 + (s&15)][kt*32 + ((s>>4)&3)*8 .. +8]:
  // exactly the 16B lane-chunk MFMA frag (s>>6) wants in lane (s&63).
  __shared__ __align__(16) unsigned short lds[3 * 16384];

  const int tid  = threadIdx.x;
  const int lane = tid & 63;
  const int wid  = tid >> 6;
  const int lrow = lane & 15;
  const int quad = lane >> 4;
  const int wm   = wid >> 2;   // 0..1 : wave m-half  (rows wm*128..+127)
  const int wn   = wid & 3;    // 0..3 : wave n-quarter (cols wn*64..+63)

  // XCD-contiguous swizzle (bijective: NWG%8==0) + GM=8 supertile raster:
  // consecutive blocks on one XCD share the same 8 A-panels while walking bn.
  const int bid = blockIdx.x;
  const int sw  = (bid & 7) * (NWG / 8) + (bid >> 3);
  const int grp = sw / (8 * NTN);
  const int rem = sw - grp * (8 * NTN);
  const int m0  = (grp * 8 + (rem & 7)) * 256;
  const int n0  = (rem >> 3) * 256;

  // Staging: thread stages A slots {tid, tid+512} and B slots {tid, tid+512}
  // (4 x 16B gload_lds per K-tile). LDS dest is linear (base + lane*16B);
  // the fragment permutation lives in the global source address.
  const int rowS = ((tid >> 6) << 4) | (tid & 15);   // 0..127
  const int kseg = ((tid >> 4) & 3) << 3;            // 0,8,16,24
  const unsigned short* pa = Xb + (size_t)(m0 + rowS) * K_IN + kseg;
  const unsigned short* pb = Wp + (size_t)(n0 + rowS) * K_IN + kseg;
  unsigned short* dA = lds + tid * 8;                // + q*16384 (ushort units)
  unsigned short* dB = lds + 8192 + tid * 8;

  // Fragment reads: frag mi at buf q -> 64 lanes read 1024 CONTIGUOUS bytes
  // (slot base + lane*16B) => zero LDS bank conflicts.
  const unsigned short* fA = lds + ((wm * 8) * 64 + lane) * 8;          // + q*16384 + mi*512
  const unsigned short* fB = lds + 8192 + ((wn * 4) * 64 + lane) * 8;   // + q*16384 + ni*512

#define STAGE_A(q, t) do {                                                                  \
    const unsigned short* s_ = pa + (size_t)(t) * 32;                                       \
    __builtin_amdgcn_global_load_lds(AS1(s_),                        AS3(dA + (q) * 16384),        16, 0, 0); \
    __builtin_amdgcn_global_load_lds(AS1(s_ + (size_t)128 * K_IN),   AS3(dA + (q) * 16384 + 4096), 16, 0, 0); \
  } while (0)
#define STAGE_B(q, t) do {                                                                  \
    const unsigned short* s_ = pb + (size_t)(t) * 32;                                       \
    __builtin_amdgcn_global_load_lds(AS1(s_),                        AS3(dB + (q) * 16384),        16, 0, 0); \
    __builtin_amdgcn_global_load_lds(AS1(s_ + (size_t)128 * K_IN),   AS3(dB + (q) * 16384 + 4096), 16, 0, 0); \
  } while (0)

  floatx4 acc[8][4];
#pragma unroll
  for (int i = 0; i < 8; ++i)
#pragma unroll
    for (int j = 0; j < 4; ++j)
      acc[i][j] = (floatx4){0.f, 0.f, 0.f, 0.f};

  // Prologue: stage tiles 0,1 (8 loads/thread), wait tile 0 (leave tile 1 in flight).
  STAGE_A(0, 0); STAGE_B(0, 0);
  STAGE_A(1, 1); STAGE_B(1, 1);
  asm volatile("s_waitcnt vmcnt(4)" ::: "memory");
  __builtin_amdgcn_s_barrier();
  asm volatile("" ::: "memory");

  int cur = 0, nxt = 2;
  for (int t = 0; t < KT; ++t) {
    const unsigned short* fAc = fA + cur * 16384;
    const unsigned short* fBc = fB + cur * 16384;

    // ---- phase 1: stage A of tile t+2; read B0-3 + A0-3; 16 MFMA (mi 0-3)
    if (t + 2 < KT) STAGE_A(nxt, t + 2);
    short8 b[4], a[4];
#pragma unroll
    for (int ni = 0; ni < 4; ++ni) b[ni] = *(const short8*)(fBc + ni * 512);
#pragma unroll
    for (int mi = 0; mi < 4; ++mi) a[mi] = *(const short8*)(fAc + mi * 512);
    __builtin_amdgcn_s_setprio(1);
#pragma unroll
    for (int mi = 0; mi < 4; ++mi)
#pragma unroll
      for (int ni = 0; ni < 4; ++ni)
        acc[mi][ni] = __builtin_amdgcn_mfma_f32_16x16x32_bf16(a[mi], b[ni], acc[mi][ni], 0, 0, 0);
    __builtin_amdgcn_s_setprio(0);

    // ---- phase 2: stage B of tile t+2; read A4-7; 16 MFMA (mi 4-7)
    if (t + 2 < KT) STAGE_B(nxt, t + 2);
    short8 a2[4];
#pragma unroll
    for (int mi = 0; mi < 4; ++mi) a2[mi] = *(const short8*)(fAc + (4 + mi) * 512);
    __builtin_amdgcn_s_setprio(1);
#pragma unroll
    for (int mi = 0; mi < 4; ++mi)
#pragma unroll
      for (int ni = 0; ni < 4; ++ni)
        acc[4 + mi][ni] = __builtin_amdgcn_mfma_f32_16x16x32_bf16(a2[mi], b[ni], acc[4 + mi][ni], 0, 0, 0);
    __builtin_amdgcn_s_setprio(0);

    // ---- tile boundary: counted wait (tile t+1 landed; tile t+2's 4 loads stay in flight)
    if (t < KT - 2) { asm volatile("s_waitcnt vmcnt(4)" ::: "memory"); }
    else           { asm volatile("s_waitcnt vmcnt(0)" ::: "memory"); }
    __builtin_amdgcn_s_barrier();
    asm volatile("" ::: "memory");

    cur = (cur == 2) ? 0 : cur + 1;
    nxt = (nxt == 2) ? 0 : nxt + 1;
  }

  // Epilogue: C/D layout col = lane&15 (n), row = quad*4 + reg (m). Fuse bias.
  float bv[4];
#pragma unroll
  for (int ni = 0; ni < 4; ++ni)
    bv[ni] = bias[n0 + wn * 64 + ni * 16 + lrow];

#pragma unroll
  for (int mi = 0; mi < 8; ++mi) {
    const int rbase = m0 + wm * 128 + mi * 16 + quad * 4;
#pragma unroll
    for (int ni = 0; ni < 4; ++ni) {
      const int col = n0 + wn * 64 + ni * 16 + lrow;
#pragma unroll
      for (int r = 0; r < 4; ++r)
        out[(size_t)(rbase + r) * N_OUT + col] = acc[mi][ni][r] + bv[ni];
    }
  }
#undef STAGE_A
#undef STAGE_B
}

extern "C" void kernel_launch(void* const* d_in, const int* in_sizes, int n_in,
                              void* d_out, int out_size, void* d_ws, size_t ws_size,
                              hipStream_t stream) {
  const float* x    = (const float*)d_in[0];
  const float* W    = (const float*)d_in[1];
  const float* bias = (const float*)d_in[2];
  const float* B    = (const float*)d_in[3];
  const float* A    = (const float*)d_in[4];
  float* out = (float*)d_out;

  // Workspace layout: [ x_bf16 : 8192*4096*2 = 64 MiB ][ W'_bf16 : 11008*4096*2 ≈ 86 MiB ]
  unsigned short* xb = (unsigned short*)d_ws;
  unsigned short* wp = (unsigned short*)((char*)d_ws + (size_t)M_TOK * K_IN * 2);

  cast_x_kernel<<<(M_TOK * K_IN / 4) / 256, 256, 0, stream>>>(
      x, (unsigned long long*)xb);
  wprime_kernel<<<dim3(N_OUT, K_IN / 1024), 256, 0, stream>>>(
      W, B, A, (unsigned long long*)wp);
  lora_gemm<<<dim3(NWG), 512, 0, stream>>>(xb, wp, bias, out);
}